// Round 19
// baseline (374.565 us; speedup 1.0000x reference)
//
#include <hip/hip_runtime.h>
#include <hip/hip_bf16.h>
#include <stdint.h>

#define D_DIM 1024
#define F_DIM 4096
#define E_NUM 8
#define BM2 256
#define BN2 128
#define BK 64
#define MAXTILES 80   // ctrl layout sizing (tile table at 256-granularity uses <= 40)
#define MAXT256 40

typedef __attribute__((ext_vector_type(4))) float f32x4;
typedef __attribute__((ext_vector_type(8))) short bf16x8;

// ctrl layout (int indices)
#define C_CNT   0                    // 8 counts
#define C_CUR   8                    // 8 cursors
#define C_OFF   16                   // 9 offsets
#define C_NT    25                   // 1 tile count
#define C_TE    26                   // tile->expert
#define C_TR    (26+MAXTILES)        // tile->row base
#define C_USAGE (26+2*MAXTILES)      // 8 floats (usage sums)

__device__ __forceinline__ void gload_lds16(const void* g, void* l) {
  __builtin_amdgcn_global_load_lds((const __attribute__((address_space(1))) void*)g,
                                   (__attribute__((address_space(3))) void*)l, 16, 0, 0);
}

__device__ __forceinline__ float bf2f(unsigned short u) {
  union { unsigned int i; float f; } c; c.i = ((unsigned int)u) << 16; return c.f;
}

// ---------------- fp32 -> bf16 conversion (vectorized) ----------------
__global__ void cvt_k(const float* __restrict__ s, unsigned short* __restrict__ d, int n4) {
  const int stride = gridDim.x * blockDim.x;
  for (int i = blockIdx.x * blockDim.x + threadIdx.x; i < n4; i += stride) {
    float4 v = ((const float4*)s)[i];
    __hip_bfloat16 h0 = __float2bfloat16(v.x);
    __hip_bfloat16 h1 = __float2bfloat16(v.y);
    __hip_bfloat16 h2 = __float2bfloat16(v.z);
    __hip_bfloat16 h3 = __float2bfloat16(v.w);
    ushort4 o;
    o.x = *(unsigned short*)&h0; o.y = *(unsigned short*)&h1;
    o.z = *(unsigned short*)&h2; o.w = *(unsigned short*)&h3;
    ((ushort4*)d)[i] = o;
  }
}

// ---------------- router: 1 wave per token; also emits bf16 x ----------------
__global__ __launch_bounds__(256) void router_k(
    const float* __restrict__ x, const float* __restrict__ Wr,
    int* __restrict__ t2i, float* __restrict__ t2g,
    float* __restrict__ usage_part, unsigned short* __restrict__ xb, int T) {
  __shared__ float us[4][E_NUM];
  const int wave = threadIdx.x >> 6;
  const int lane = threadIdx.x & 63;
  const int gw = blockIdx.x * 4 + wave;   // token
  const float4* xt = (const float4*)(x + (size_t)gw * D_DIM);
  const float4* wr4 = (const float4*)Wr;
  unsigned short* xrow = xb + (size_t)gw * D_DIM;
  float l[E_NUM] = {0.f,0.f,0.f,0.f,0.f,0.f,0.f,0.f};
#pragma unroll
  for (int it = 0; it < D_DIM / 256; it++) {
    const int i4 = it * 64 + lane;
    const float4 xv = xt[i4];
    __hip_bfloat16 c0 = __float2bfloat16(xv.x), c1 = __float2bfloat16(xv.y);
    __hip_bfloat16 c2 = __float2bfloat16(xv.z), c3 = __float2bfloat16(xv.w);
    ushort4 ov; ov.x = *(unsigned short*)&c0; ov.y = *(unsigned short*)&c1;
    ov.z = *(unsigned short*)&c2; ov.w = *(unsigned short*)&c3;
    ((ushort4*)xrow)[i4] = ov;
#pragma unroll
    for (int e = 0; e < E_NUM; e++) {
      const float4 w = wr4[e * (D_DIM / 4) + i4];
      l[e] += xv.x * w.x + xv.y * w.y + xv.z * w.z + xv.w * w.w;
    }
  }
#pragma unroll
  for (int e = 0; e < E_NUM; e++) {
    float v = l[e];
    v += __shfl_xor(v, 32); v += __shfl_xor(v, 16); v += __shfl_xor(v, 8);
    v += __shfl_xor(v, 4);  v += __shfl_xor(v, 2);  v += __shfl_xor(v, 1);
    l[e] = v;
  }
  float m = l[0];
#pragma unroll
  for (int e = 1; e < E_NUM; e++) m = fmaxf(m, l[e]);
  float p[E_NUM]; float s = 0.f;
#pragma unroll
  for (int e = 0; e < E_NUM; e++) { p[e] = expf(l[e] - m); s += p[e]; }
  const float inv = 1.0f / s;
  float v1 = l[0]; int i1 = 0;
#pragma unroll
  for (int e = 1; e < E_NUM; e++) { if (l[e] > v1) { v1 = l[e]; i1 = e; } }
  float v2 = -3.0e38f; int i2 = 0;
#pragma unroll
  for (int e = 0; e < E_NUM; e++) { if (e != i1 && l[e] > v2) { v2 = l[e]; i2 = e; } }
  const float p1 = expf(v1 - m);
  const float p2 = expf(v2 - m);
  const float gd = 1.0f / (p1 + p2);
  if (lane == 0) {
    t2i[gw * 2] = i1; t2i[gw * 2 + 1] = i2;
    t2g[gw * 2] = p1 * gd; t2g[gw * 2 + 1] = p2 * gd;
#pragma unroll
    for (int e = 0; e < E_NUM; e++) us[wave][e] = p[e] * inv;
  }
  __syncthreads();
  if (threadIdx.x < E_NUM) {
    const int e = threadIdx.x;
    usage_part[blockIdx.x * E_NUM + e] = us[0][e] + us[1][e] + us[2][e] + us[3][e];
  }
}

// ---------------- reduce + offsets + tile table + aux loss (merged) ----------------
__global__ __launch_bounds__(256) void reduce_k(
    const float* __restrict__ usage_part, const int* __restrict__ t2i,
    int* __restrict__ ctrl, float* __restrict__ aux_out, int nblk, int T2, int T) {
  __shared__ float usum[E_NUM];
  __shared__ int hist[E_NUM];
  if (threadIdx.x < E_NUM) { usum[threadIdx.x] = 0.f; hist[threadIdx.x] = 0; }
  __syncthreads();
  {
    const int e = threadIdx.x & 7;
    const int chunk = threadIdx.x >> 3;
    float s = 0.f;
    for (int i = chunk; i < nblk; i += 32) s += usage_part[i * E_NUM + e];
    atomicAdd(&usum[e], s);
  }
  {
    int h[E_NUM] = {0,0,0,0,0,0,0,0};
    for (int i = threadIdx.x; i < T2; i += 256) h[t2i[i] & 7]++;
#pragma unroll
    for (int e = 0; e < E_NUM; e++) if (h[e]) atomicAdd(&hist[e], h[e]);
  }
  __syncthreads();
  if (threadIdx.x == 0) {
    int off = 0, nt = 0;
    float loss = 0.f;
    for (int e = 0; e < E_NUM; e++) {
      ctrl[C_CNT + e] = hist[e];
      ctrl[C_OFF + e] = off;
      ctrl[C_CUR + e] = off;
      const int c = hist[e];
      const int ntile = (c + BM2 - 1) / BM2;
      for (int i = 0; i < ntile; i++) {
        ctrl[C_TE + nt] = e;
        ctrl[C_TR + nt] = off + i * BM2;
        nt++;
      }
      off += c;
      const float um = usum[e] / (float)T - 1.0f / (float)E_NUM;
      loss += um * um;
    }
    ctrl[C_OFF + E_NUM] = off;
    ctrl[C_NT] = nt;
    aux_out[0] = 0.01f * loss;
  }
}

// ---------------- scatter tokens to per-expert slots ----------------
__global__ void scatter_k(const int* __restrict__ t2i, int* __restrict__ ctrl,
                          int* __restrict__ rmap, int* __restrict__ slots, int T) {
  const int t = blockIdx.x * blockDim.x + threadIdx.x;
  if (t >= T) return;
#pragma unroll
  for (int k = 0; k < 2; k++) {
    const int e = t2i[t * 2 + k];
    const int slot = atomicAdd(&ctrl[C_CUR + e], 1);
    rmap[slot] = t;
    slots[t * 2 + k] = slot;
  }
}

// ====== 256x128-tile SINGLE-buffer GEMM, 48 KiB LDS -> multi-block/CU (R18-proven) ======
#define STAGE(K0)                                                    \
  {                                                                  \
    _Pragma("unroll")                                                \
    for (int i = 0; i < 4; i++) gload_lds16(a_src[i] + (K0), aL[i]); \
    _Pragma("unroll")                                                \
    for (int j = 0; j < 2; j++) gload_lds16(b_src[j] + (K0), bL[j]); \
  }

#define COMPUTE(AC, BC)                                              \
  {                                                                  \
    _Pragma("unroll")                                                \
    for (int kh = 0; kh < 2; ++kh) {                                 \
      const int co = (((kh * 4 + ckq) ^ swz) << 4);                  \
      bf16x8 af[8], bfv[2];                                          \
      _Pragma("unroll")                                              \
      for (int mi = 0; mi < 8; mi++)                                 \
        af[mi] = *(const bf16x8*)((AC) + (rA + mi * 16) * 128 + co); \
      _Pragma("unroll")                                              \
      for (int ni = 0; ni < 2; ni++)                                 \
        bfv[ni] = *(const bf16x8*)((BC) + (rB + ni * 16) * 128 + co);\
      _Pragma("unroll")                                              \
      for (int mi = 0; mi < 8; mi++)                                 \
        _Pragma("unroll")                                            \
        for (int ni = 0; ni < 2; ni++)                               \
          acc[mi][ni] = __builtin_amdgcn_mfma_f32_16x16x32_bf16(af[mi], bfv[ni], acc[mi][ni], 0, 0, 0); \
    }                                                                \
  }

// ---------------- GEMM1: h = gelu(x @ W1[e]^T + b1[e]), 256x128 tile ----------------
__global__ __launch_bounds__(512, 2) void gemm1_k(
    const unsigned short* __restrict__ xb, const unsigned short* __restrict__ W1b,
    const float* __restrict__ b1, unsigned short* __restrict__ hb,
    const int* __restrict__ rmap, const int* __restrict__ ctrl, int T2) {
  extern __shared__ char smem[];   // A 32K + B 16K = 48 KiB
  // grid = 40*32 = 1280; XCD-chunked remap (1280 = 8*160)
  const int lin = blockIdx.x;
  const int lin2 = (lin & 7) * 160 + (lin >> 3);
  const int tile = lin2 >> 5;
  const int fbase = (lin2 & 31) * BN2;

  const int nt = ctrl[C_NT];
  if (tile >= nt) return;
  const int e = ctrl[C_TE + tile];
  const int rowbase = ctrl[C_TR + tile];
  const int row_end = ctrl[C_OFF + e + 1];

  const int tid = threadIdx.x;
  const int lane = tid & 63;
  const int wave = tid >> 6;

  const unsigned short* a_src[4];
  const unsigned short* b_src[2];
  char *aL[4], *bL[2];
#pragma unroll
  for (int i = 0; i < 4; i++) {
    const int c = tid + 512 * i;           // 0..2047 (A chunks)
    const int r = c >> 3, cc = c & 7;
    const int sc = cc ^ (r & 7);           // inverse-swizzled global source chunk
    int pos = rowbase + r; pos = pos < T2 ? pos : T2 - 1;
    a_src[i] = xb + (size_t)rmap[pos] * D_DIM + sc * 8;
    aL[i] = smem + c * 16;
  }
#pragma unroll
  for (int j = 0; j < 2; j++) {
    const int c2 = tid + 512 * j;          // 0..1023 (B chunks)
    const int r = c2 >> 3, cc = c2 & 7;
    const int sc = cc ^ (r & 7);
    b_src[j] = W1b + ((size_t)e * F_DIM + (size_t)(fbase + r)) * D_DIM + sc * 8;
    bL[j] = smem + 32768 + c2 * 16;
  }
  const char* As = smem;
  const char* Bs = smem + 32768;

  f32x4 acc[8][2] = {};
  const int wm = wave >> 2, wn = wave & 3;
  const int rA = wm * 128 + (lane & 15);
  const int rB = wn * 32 + (lane & 15);
  const int swz = lane & 7;            // == row&7 for all frag rows
  const int ckq = lane >> 4;           // 16B chunk quarter index

  const int NK = D_DIM / BK;           // 16
  for (int kt = 0; kt < NK; ++kt) {
    STAGE(kt * BK);
    asm volatile("s_waitcnt vmcnt(0)" ::: "memory");
    __builtin_amdgcn_s_barrier();
    __builtin_amdgcn_sched_barrier(0);
    COMPUTE(As, Bs);
    __builtin_amdgcn_sched_barrier(0);
    __builtin_amdgcn_s_barrier();
  }

  const int r_rem = row_end - rowbase;
  const float* b1e = b1 + (size_t)e * F_DIM;
  float bias[2];
#pragma unroll
  for (int ni = 0; ni < 2; ni++)
    bias[ni] = b1e[fbase + wn * 32 + ni * 16 + (lane & 15)];
#pragma unroll
  for (int mi = 0; mi < 8; mi++) {
#pragma unroll
    for (int q = 0; q < 4; q++) {
      const int rr = wm * 128 + mi * 16 + (lane >> 4) * 4 + q;
      if (rr < r_rem) {
        unsigned short* hrow = hb + (size_t)(rowbase + rr) * F_DIM;
#pragma unroll
        for (int ni = 0; ni < 2; ni++) {
          const int col = fbase + wn * 32 + ni * 16 + (lane & 15);
          const float v = acc[mi][ni][q] + bias[ni];
          const float u2 = 1.5957691216057308f * (v + 0.044715f * v * v * v);
          const float gg = v / (1.0f + __expf(-u2));   // == 0.5v(1+tanh(u))
          __hip_bfloat16 hv = __float2bfloat16(gg);
          hrow[col] = *(unsigned short*)&hv;
        }
      }
    }
  }
}

// ---------------- GEMM2 (K-split x2): y2[z][slot] = h @ W2[e]^T partial, 256x128 tile ----------------
__global__ __launch_bounds__(512, 2) void gemm2_k(
    const unsigned short* __restrict__ hb, const unsigned short* __restrict__ W2b,
    unsigned short* __restrict__ y2, const int* __restrict__ ctrl, int T2) {
  extern __shared__ char smem[];
  // grid = 40*8*2 = 640; XCD-chunked remap (640 = 8*80)
  const int lin = blockIdx.x;
  const int lin2 = (lin & 7) * 80 + (lin >> 3);
  const int tile = lin2 >> 4;
  const int rest = lin2 & 15;
  const int z = rest >> 3;               // 0..1
  const int dbase = (rest & 7) * BN2;    // 0..896

  const int nt = ctrl[C_NT];
  if (tile >= nt) return;
  const int e = ctrl[C_TE + tile];
  const int rowbase = ctrl[C_TR + tile];
  const int row_end = ctrl[C_OFF + e + 1];
  const int kt0 = z * (F_DIM / BK / 2);   // 0 or 32

  const int tid = threadIdx.x;
  const int lane = tid & 63;
  const int wave = tid >> 6;

  const unsigned short* a_src[4];
  const unsigned short* b_src[2];
  char *aL[4], *bL[2];
#pragma unroll
  for (int i = 0; i < 4; i++) {
    const int c = tid + 512 * i;
    const int r = c >> 3, cc = c & 7;
    const int sc = cc ^ (r & 7);
    int pos = rowbase + r; pos = pos < T2 ? pos : T2 - 1;
    a_src[i] = hb + (size_t)pos * F_DIM + sc * 8;
    aL[i] = smem + c * 16;
  }
#pragma unroll
  for (int j = 0; j < 2; j++) {
    const int c2 = tid + 512 * j;
    const int r = c2 >> 3, cc = c2 & 7;
    const int sc = cc ^ (r & 7);
    b_src[j] = W2b + ((size_t)e * D_DIM + (size_t)(dbase + r)) * F_DIM + sc * 8;
    bL[j] = smem + 32768 + c2 * 16;
  }
  const char* As = smem;
  const char* Bs = smem + 32768;

  f32x4 acc[8][2] = {};
  const int wm = wave >> 2, wn = wave & 3;
  const int rA = wm * 128 + (lane & 15);
  const int rB = wn * 32 + (lane & 15);
  const int swz = lane & 7;
  const int ckq = lane >> 4;

  const int NKH = F_DIM / BK / 2;      // 32
  for (int kt = kt0; kt < kt0 + NKH; ++kt) {
    STAGE(kt * BK);
    asm volatile("s_waitcnt vmcnt(0)" ::: "memory");
    __builtin_amdgcn_s_barrier();
    __builtin_amdgcn_sched_barrier(0);
    COMPUTE(As, Bs);
    __builtin_amdgcn_sched_barrier(0);
    __builtin_amdgcn_s_barrier();
  }

  const int r_rem = row_end - rowbase;
  unsigned short* yz = y2 + (size_t)z * T2 * D_DIM;
#pragma unroll
  for (int mi = 0; mi < 8; mi++) {
#pragma unroll
    for (int q = 0; q < 4; q++) {
      const int rr = wm * 128 + mi * 16 + (lane >> 4) * 4 + q;
      if (rr < r_rem) {
        unsigned short* yrow = yz + (size_t)(rowbase + rr) * D_DIM;
#pragma unroll
        for (int ni = 0; ni < 2; ni++) {
          const int col = dbase + wn * 32 + ni * 16 + (lane & 15);
          __hip_bfloat16 hv = __float2bfloat16(acc[mi][ni][q]);
          yrow[col] = *(unsigned short*)&hv;
        }
      }
    }
  }
}

// ---------------- combine: out[t] = sum_k g_k * (sum_z y2[z][s_k] + b2[e_k]) ----------------
__global__ __launch_bounds__(256) void combine_k(
    const unsigned short* __restrict__ y2, const float* __restrict__ b2,
    const int* __restrict__ t2i, const float* __restrict__ t2g,
    const int* __restrict__ slots, float* __restrict__ out, int T2) {
  const int t = blockIdx.x;
  const int c4 = threadIdx.x;   // 256 threads x float4 = 1024 cols
  const int s0 = slots[t * 2], s1 = slots[t * 2 + 1];
  const int e0 = t2i[t * 2], e1 = t2i[t * 2 + 1];
  const float g0 = t2g[t * 2], g1 = t2g[t * 2 + 1];
  const size_t sl = (size_t)T2 * D_DIM;
  float sum0[4] = {0.f,0.f,0.f,0.f}, sum1[4] = {0.f,0.f,0.f,0.f};
#pragma unroll
  for (int zz = 0; zz < 2; zz++) {
    ushort4 a = ((const ushort4*)(y2 + zz * sl + (size_t)s0 * D_DIM))[c4];
    ushort4 b = ((const ushort4*)(y2 + zz * sl + (size_t)s1 * D_DIM))[c4];
    sum0[0] += bf2f(a.x); sum0[1] += bf2f(a.y); sum0[2] += bf2f(a.z); sum0[3] += bf2f(a.w);
    sum1[0] += bf2f(b.x); sum1[1] += bf2f(b.y); sum1[2] += bf2f(b.z); sum1[3] += bf2f(b.w);
  }
  float4 bb0 = ((const float4*)(b2 + (size_t)e0 * D_DIM))[c4];
  float4 bb1 = ((const float4*)(b2 + (size_t)e1 * D_DIM))[c4];
  float4 o;
  o.x = g0 * (sum0[0] + bb0.x) + g1 * (sum1[0] + bb1.x);
  o.y = g0 * (sum0[1] + bb0.y) + g1 * (sum1[1] + bb1.y);
  o.z = g0 * (sum0[2] + bb0.z) + g1 * (sum1[2] + bb1.z);
  o.w = g0 * (sum0[3] + bb0.w) + g1 * (sum1[3] + bb1.w);
  ((float4*)(out + (size_t)t * D_DIM))[c4] = o;
}

extern "C" void kernel_launch(void* const* d_in, const int* in_sizes, int n_in,
                              void* d_out, int out_size, void* d_ws, size_t ws_size,
                              hipStream_t stream) {
  const float* x  = (const float*)d_in[0];
  const float* Wr = (const float*)d_in[1];
  const float* W1 = (const float*)d_in[2];
  const float* b1 = (const float*)d_in[3];
  const float* W2 = (const float*)d_in[4];
  const float* b2 = (const float*)d_in[5];
  float* out = (float*)d_out;

  const int T = in_sizes[0] / D_DIM;  // 4096
  const int T2 = T * 2;
  const int nblk = T / 4;

  char* ws = (char*)d_ws;
  size_t o = 0;
  unsigned short* xb  = (unsigned short*)(ws + o); o += (size_t)T * D_DIM * 2;
  unsigned short* W1b = (unsigned short*)(ws + o); o += (size_t)E_NUM * F_DIM * D_DIM * 2;
  unsigned short* W2b = (unsigned short*)(ws + o); o += (size_t)E_NUM * D_DIM * F_DIM * 2;
  unsigned short* hb  = (unsigned short*)(ws + o); o += (size_t)T2 * F_DIM * 2;
  int*   ctrl  = (int*)(ws + o);   o += 4096;
  int*   t2i   = (int*)(ws + o);   o += (size_t)T2 * 4;
  float* t2g   = (float*)(ws + o); o += (size_t)T2 * 4;
  int*   rmap  = (int*)(ws + o);   o += (size_t)T2 * 4;
  int*   slots = (int*)(ws + o);   o += (size_t)T2 * 4;
  float* usage_part = (float*)(ws + o); o += (size_t)nblk * E_NUM * 4;
  // y2 (2 x T2 x D bf16 = 33.5 MB) overlays W1b (67 MB) -- W1b is dead after gemm1.
  unsigned short* y2 = W1b;

  hipFuncSetAttribute((const void*)gemm1_k, hipFuncAttributeMaxDynamicSharedMemorySize, 49152);
  hipFuncSetAttribute((const void*)gemm2_k, hipFuncAttributeMaxDynamicSharedMemorySize, 49152);

  hipMemsetAsync(ctrl, 0, 4096, stream);

  cvt_k<<<1024, 256, 0, stream>>>(W1, W1b, E_NUM * F_DIM * D_DIM / 4);
  cvt_k<<<1024, 256, 0, stream>>>(W2, W2b, E_NUM * D_DIM * F_DIM / 4);

  router_k<<<nblk, 256, 0, stream>>>(x, Wr, t2i, t2g, usage_part, xb, T);
  reduce_k<<<1, 256, 0, stream>>>(usage_part, t2i, ctrl, out + (size_t)(out_size - 1), nblk, T2, T);
  scatter_k<<<(T + 255) / 256, 256, 0, stream>>>(t2i, ctrl, rmap, slots, T);

  gemm1_k<<<MAXT256 * 32, 512, 49152, stream>>>(xb, W1b, b1, hb, rmap, ctrl, T2);
  gemm2_k<<<MAXT256 * 16, 512, 49152, stream>>>(hb, W2b, y2, ctrl, T2);
  combine_k<<<T, 256, 0, stream>>>(y2, b2, t2i, t2g, slots, out, T2);
}

// Round 20
// 360.044 us; speedup vs baseline: 1.0403x; 1.0403x over previous
//
#include <hip/hip_runtime.h>
#include <hip/hip_bf16.h>
#include <stdint.h>

#define D_DIM 1024
#define F_DIM 4096
#define E_NUM 8
#define BM2 256
#define BN2 128
#define BK 64
#define MAXTILES 80   // ctrl layout sizing (tile table at 256-granularity uses <= 40)
#define MAXT256 40

typedef __attribute__((ext_vector_type(4))) float f32x4;
typedef __attribute__((ext_vector_type(8))) short bf16x8;

// ctrl layout (int indices)
#define C_CNT   0                    // 8 counts
#define C_CUR   8                    // 8 cursors
#define C_OFF   16                   // 9 offsets
#define C_NT    25                   // 1 tile count
#define C_TE    26                   // tile->expert
#define C_TR    (26+MAXTILES)        // tile->row base
#define C_USAGE (26+2*MAXTILES)      // 8 floats (usage sums)

__device__ __forceinline__ void gload_lds16(const void* g, void* l) {
  __builtin_amdgcn_global_load_lds((const __attribute__((address_space(1))) void*)g,
                                   (__attribute__((address_space(3))) void*)l, 16, 0, 0);
}

__device__ __forceinline__ float bf2f(unsigned short u) {
  union { unsigned int i; float f; } c; c.i = ((unsigned int)u) << 16; return c.f;
}

// ---------------- fp32 -> bf16 conversion (vectorized) ----------------
__global__ void cvt_k(const float* __restrict__ s, unsigned short* __restrict__ d, int n4) {
  const int stride = gridDim.x * blockDim.x;
  for (int i = blockIdx.x * blockDim.x + threadIdx.x; i < n4; i += stride) {
    float4 v = ((const float4*)s)[i];
    __hip_bfloat16 h0 = __float2bfloat16(v.x);
    __hip_bfloat16 h1 = __float2bfloat16(v.y);
    __hip_bfloat16 h2 = __float2bfloat16(v.z);
    __hip_bfloat16 h3 = __float2bfloat16(v.w);
    ushort4 o;
    o.x = *(unsigned short*)&h0; o.y = *(unsigned short*)&h1;
    o.z = *(unsigned short*)&h2; o.w = *(unsigned short*)&h3;
    ((ushort4*)d)[i] = o;
  }
}

// ---------------- router: 1 wave per token; also emits bf16 x ----------------
__global__ __launch_bounds__(256) void router_k(
    const float* __restrict__ x, const float* __restrict__ Wr,
    int* __restrict__ t2i, float* __restrict__ t2g,
    float* __restrict__ usage_part, unsigned short* __restrict__ xb, int T) {
  __shared__ float us[4][E_NUM];
  const int wave = threadIdx.x >> 6;
  const int lane = threadIdx.x & 63;
  const int gw = blockIdx.x * 4 + wave;   // token
  const float4* xt = (const float4*)(x + (size_t)gw * D_DIM);
  const float4* wr4 = (const float4*)Wr;
  unsigned short* xrow = xb + (size_t)gw * D_DIM;
  float l[E_NUM] = {0.f,0.f,0.f,0.f,0.f,0.f,0.f,0.f};
#pragma unroll
  for (int it = 0; it < D_DIM / 256; it++) {
    const int i4 = it * 64 + lane;
    const float4 xv = xt[i4];
    __hip_bfloat16 c0 = __float2bfloat16(xv.x), c1 = __float2bfloat16(xv.y);
    __hip_bfloat16 c2 = __float2bfloat16(xv.z), c3 = __float2bfloat16(xv.w);
    ushort4 ov; ov.x = *(unsigned short*)&c0; ov.y = *(unsigned short*)&c1;
    ov.z = *(unsigned short*)&c2; ov.w = *(unsigned short*)&c3;
    ((ushort4*)xrow)[i4] = ov;
#pragma unroll
    for (int e = 0; e < E_NUM; e++) {
      const float4 w = wr4[e * (D_DIM / 4) + i4];
      l[e] += xv.x * w.x + xv.y * w.y + xv.z * w.z + xv.w * w.w;
    }
  }
#pragma unroll
  for (int e = 0; e < E_NUM; e++) {
    float v = l[e];
    v += __shfl_xor(v, 32); v += __shfl_xor(v, 16); v += __shfl_xor(v, 8);
    v += __shfl_xor(v, 4);  v += __shfl_xor(v, 2);  v += __shfl_xor(v, 1);
    l[e] = v;
  }
  float m = l[0];
#pragma unroll
  for (int e = 1; e < E_NUM; e++) m = fmaxf(m, l[e]);
  float p[E_NUM]; float s = 0.f;
#pragma unroll
  for (int e = 0; e < E_NUM; e++) { p[e] = expf(l[e] - m); s += p[e]; }
  const float inv = 1.0f / s;
  float v1 = l[0]; int i1 = 0;
#pragma unroll
  for (int e = 1; e < E_NUM; e++) { if (l[e] > v1) { v1 = l[e]; i1 = e; } }
  float v2 = -3.0e38f; int i2 = 0;
#pragma unroll
  for (int e = 0; e < E_NUM; e++) { if (e != i1 && l[e] > v2) { v2 = l[e]; i2 = e; } }
  const float p1 = expf(v1 - m);
  const float p2 = expf(v2 - m);
  const float gd = 1.0f / (p1 + p2);
  if (lane == 0) {
    t2i[gw * 2] = i1; t2i[gw * 2 + 1] = i2;
    t2g[gw * 2] = p1 * gd; t2g[gw * 2 + 1] = p2 * gd;
#pragma unroll
    for (int e = 0; e < E_NUM; e++) us[wave][e] = p[e] * inv;
  }
  __syncthreads();
  if (threadIdx.x < E_NUM) {
    const int e = threadIdx.x;
    usage_part[blockIdx.x * E_NUM + e] = us[0][e] + us[1][e] + us[2][e] + us[3][e];
  }
}

// ---------------- reduce + offsets + tile table + aux loss (merged) ----------------
__global__ __launch_bounds__(256) void reduce_k(
    const float* __restrict__ usage_part, const int* __restrict__ t2i,
    int* __restrict__ ctrl, float* __restrict__ aux_out, int nblk, int T2, int T) {
  __shared__ float usum[E_NUM];
  __shared__ int hist[E_NUM];
  if (threadIdx.x < E_NUM) { usum[threadIdx.x] = 0.f; hist[threadIdx.x] = 0; }
  __syncthreads();
  {
    const int e = threadIdx.x & 7;
    const int chunk = threadIdx.x >> 3;
    float s = 0.f;
    for (int i = chunk; i < nblk; i += 32) s += usage_part[i * E_NUM + e];
    atomicAdd(&usum[e], s);
  }
  {
    int h[E_NUM] = {0,0,0,0,0,0,0,0};
    for (int i = threadIdx.x; i < T2; i += 256) h[t2i[i] & 7]++;
#pragma unroll
    for (int e = 0; e < E_NUM; e++) if (h[e]) atomicAdd(&hist[e], h[e]);
  }
  __syncthreads();
  if (threadIdx.x == 0) {
    int off = 0, nt = 0;
    float loss = 0.f;
    for (int e = 0; e < E_NUM; e++) {
      ctrl[C_CNT + e] = hist[e];
      ctrl[C_OFF + e] = off;
      ctrl[C_CUR + e] = off;
      const int c = hist[e];
      const int ntile = (c + BM2 - 1) / BM2;
      for (int i = 0; i < ntile; i++) {
        ctrl[C_TE + nt] = e;
        ctrl[C_TR + nt] = off + i * BM2;
        nt++;
      }
      off += c;
      const float um = usum[e] / (float)T - 1.0f / (float)E_NUM;
      loss += um * um;
    }
    ctrl[C_OFF + E_NUM] = off;
    ctrl[C_NT] = nt;
    aux_out[0] = 0.01f * loss;
  }
}

// ---------------- scatter tokens to per-expert slots ----------------
__global__ void scatter_k(const int* __restrict__ t2i, int* __restrict__ ctrl,
                          int* __restrict__ rmap, int* __restrict__ slots, int T) {
  const int t = blockIdx.x * blockDim.x + threadIdx.x;
  if (t >= T) return;
#pragma unroll
  for (int k = 0; k < 2; k++) {
    const int e = t2i[t * 2 + k];
    const int slot = atomicAdd(&ctrl[C_CUR + e], 1);
    rmap[slot] = t;
    slots[t * 2 + k] = slot;
  }
}

// ====== 256x128-tile SINGLE-buffer GEMM, 48 KiB LDS -> multi-block/CU (R18-proven) ======
// Per K-step: 6 gload_lds -> vmcnt(0) -> bar -> 64 MFMA -> bar. The vmcnt(0) drain
// is hidden by the OTHER co-resident blocks' waves (m114 cross-block overlap).

#define STAGE(K0)                                                    \
  {                                                                  \
    _Pragma("unroll")                                                \
    for (int i = 0; i < 4; i++) gload_lds16(a_src[i] + (K0), aL[i]); \
    _Pragma("unroll")                                                \
    for (int j = 0; j < 2; j++) gload_lds16(b_src[j] + (K0), bL[j]); \
  }

#define COMPUTE(AC, BC)                                              \
  {                                                                  \
    _Pragma("unroll")                                                \
    for (int kh = 0; kh < 2; ++kh) {                                 \
      const int co = (((kh * 4 + ckq) ^ swz) << 4);                  \
      bf16x8 af[8], bfv[2];                                          \
      _Pragma("unroll")                                              \
      for (int mi = 0; mi < 8; mi++)                                 \
        af[mi] = *(const bf16x8*)((AC) + (rA + mi * 16) * 128 + co); \
      _Pragma("unroll")                                              \
      for (int ni = 0; ni < 2; ni++)                                 \
        bfv[ni] = *(const bf16x8*)((BC) + (rB + ni * 16) * 128 + co);\
      _Pragma("unroll")                                              \
      for (int mi = 0; mi < 8; mi++)                                 \
        _Pragma("unroll")                                            \
        for (int ni = 0; ni < 2; ni++)                               \
          acc[mi][ni] = __builtin_amdgcn_mfma_f32_16x16x32_bf16(af[mi], bfv[ni], acc[mi][ni], 0, 0, 0); \
    }                                                                \
  }

// ---------------- GEMM1: h = gelu(x @ W1[e]^T + b1[e]), 256x128 tile ----------------
__global__ __launch_bounds__(512, 2) void gemm1_k(
    const unsigned short* __restrict__ xb, const unsigned short* __restrict__ W1b,
    const float* __restrict__ b1, unsigned short* __restrict__ hb,
    const int* __restrict__ rmap, const int* __restrict__ ctrl, int T2) {
  extern __shared__ char smem[];   // A 32K + B 16K = 48 KiB
  // grid = 40*32 = 1280; XCD-chunked remap (1280 = 8*160)
  const int lin = blockIdx.x;
  const int lin2 = (lin & 7) * 160 + (lin >> 3);
  const int tile = lin2 >> 5;
  const int fbase = (lin2 & 31) * BN2;

  const int nt = ctrl[C_NT];
  if (tile >= nt) return;
  const int e = ctrl[C_TE + tile];
  const int rowbase = ctrl[C_TR + tile];
  const int row_end = ctrl[C_OFF + e + 1];

  const int tid = threadIdx.x;
  const int lane = tid & 63;
  const int wave = tid >> 6;

  const unsigned short* a_src[4];
  const unsigned short* b_src[2];
  char *aL[4], *bL[2];
#pragma unroll
  for (int i = 0; i < 4; i++) {
    const int c = tid + 512 * i;           // 0..2047 (A chunks)
    const int r = c >> 3, cc = c & 7;
    const int sc = cc ^ (r & 7);           // inverse-swizzled global source chunk
    int pos = rowbase + r; pos = pos < T2 ? pos : T2 - 1;
    a_src[i] = xb + (size_t)rmap[pos] * D_DIM + sc * 8;
    aL[i] = smem + c * 16;
  }
#pragma unroll
  for (int j = 0; j < 2; j++) {
    const int c2 = tid + 512 * j;          // 0..1023 (B chunks)
    const int r = c2 >> 3, cc = c2 & 7;
    const int sc = cc ^ (r & 7);
    b_src[j] = W1b + ((size_t)e * F_DIM + (size_t)(fbase + r)) * D_DIM + sc * 8;
    bL[j] = smem + 32768 + c2 * 16;
  }
  const char* As = smem;
  const char* Bs = smem + 32768;

  f32x4 acc[8][2] = {};
  const int wm = wave >> 2, wn = wave & 3;
  const int rA = wm * 128 + (lane & 15);
  const int rB = wn * 32 + (lane & 15);
  const int swz = lane & 7;            // == row&7 for all frag rows
  const int ckq = lane >> 4;           // 16B chunk quarter index

  const int NK = D_DIM / BK;           // 16
  for (int kt = 0; kt < NK; ++kt) {
    STAGE(kt * BK);
    asm volatile("s_waitcnt vmcnt(0)" ::: "memory");
    __builtin_amdgcn_s_barrier();
    __builtin_amdgcn_sched_barrier(0);
    COMPUTE(As, Bs);
    __builtin_amdgcn_sched_barrier(0);
    __builtin_amdgcn_s_barrier();
  }

  const int r_rem = row_end - rowbase;
  const float* b1e = b1 + (size_t)e * F_DIM;
  float bias[2];
#pragma unroll
  for (int ni = 0; ni < 2; ni++)
    bias[ni] = b1e[fbase + wn * 32 + ni * 16 + (lane & 15)];
#pragma unroll
  for (int mi = 0; mi < 8; mi++) {
#pragma unroll
    for (int q = 0; q < 4; q++) {
      const int rr = wm * 128 + mi * 16 + (lane >> 4) * 4 + q;
      if (rr < r_rem) {
        unsigned short* hrow = hb + (size_t)(rowbase + rr) * F_DIM;
#pragma unroll
        for (int ni = 0; ni < 2; ni++) {
          const int col = fbase + wn * 32 + ni * 16 + (lane & 15);
          const float v = acc[mi][ni][q] + bias[ni];
          const float u2 = 1.5957691216057308f * (v + 0.044715f * v * v * v);
          const float gg = v / (1.0f + __expf(-u2));   // == 0.5v(1+tanh(u))
          __hip_bfloat16 hv = __float2bfloat16(gg);
          hrow[col] = *(unsigned short*)&hv;
        }
      }
    }
  }
}

// ---------------- GEMM2 (K-split x4): y2[z][slot] = h @ W2[e]^T partial, 256x128 tile ----------------
__global__ __launch_bounds__(512, 2) void gemm2_k(
    const unsigned short* __restrict__ hb, const unsigned short* __restrict__ W2b,
    unsigned short* __restrict__ y2, const int* __restrict__ ctrl, int T2) {
  extern __shared__ char smem[];
  // grid = 40*32 = 1280; XCD-chunked remap (1280 = 8*160)
  const int lin = blockIdx.x;
  const int lin2 = (lin & 7) * 160 + (lin >> 3);
  const int tile = lin2 >> 5;
  const int rest = lin2 & 31;
  const int z = rest >> 3;               // 0..3
  const int dbase = (rest & 7) * BN2;    // 0..896

  const int nt = ctrl[C_NT];
  if (tile >= nt) return;
  const int e = ctrl[C_TE + tile];
  const int rowbase = ctrl[C_TR + tile];
  const int row_end = ctrl[C_OFF + e + 1];
  const int kt0 = z * (F_DIM / BK / 4);   // 0,16,32,48

  const int tid = threadIdx.x;
  const int lane = tid & 63;
  const int wave = tid >> 6;

  const unsigned short* a_src[4];
  const unsigned short* b_src[2];
  char *aL[4], *bL[2];
#pragma unroll
  for (int i = 0; i < 4; i++) {
    const int c = tid + 512 * i;
    const int r = c >> 3, cc = c & 7;
    const int sc = cc ^ (r & 7);
    int pos = rowbase + r; pos = pos < T2 ? pos : T2 - 1;
    a_src[i] = hb + (size_t)pos * F_DIM + sc * 8;
    aL[i] = smem + c * 16;
  }
#pragma unroll
  for (int j = 0; j < 2; j++) {
    const int c2 = tid + 512 * j;
    const int r = c2 >> 3, cc = c2 & 7;
    const int sc = cc ^ (r & 7);
    b_src[j] = W2b + ((size_t)e * D_DIM + (size_t)(dbase + r)) * F_DIM + sc * 8;
    bL[j] = smem + 32768 + c2 * 16;
  }
  const char* As = smem;
  const char* Bs = smem + 32768;

  f32x4 acc[8][2] = {};
  const int wm = wave >> 2, wn = wave & 3;
  const int rA = wm * 128 + (lane & 15);
  const int rB = wn * 32 + (lane & 15);
  const int swz = lane & 7;
  const int ckq = lane >> 4;

  const int NKH = F_DIM / BK / 4;      // 16
  for (int kt = kt0; kt < kt0 + NKH; ++kt) {
    STAGE(kt * BK);
    asm volatile("s_waitcnt vmcnt(0)" ::: "memory");
    __builtin_amdgcn_s_barrier();
    __builtin_amdgcn_sched_barrier(0);
    COMPUTE(As, Bs);
    __builtin_amdgcn_sched_barrier(0);
    __builtin_amdgcn_s_barrier();
  }

  const int r_rem = row_end - rowbase;
  unsigned short* yz = y2 + (size_t)z * T2 * D_DIM;
#pragma unroll
  for (int mi = 0; mi < 8; mi++) {
#pragma unroll
    for (int q = 0; q < 4; q++) {
      const int rr = wm * 128 + mi * 16 + (lane >> 4) * 4 + q;
      if (rr < r_rem) {
        unsigned short* yrow = yz + (size_t)(rowbase + rr) * D_DIM;
#pragma unroll
        for (int ni = 0; ni < 2; ni++) {
          const int col = dbase + wn * 32 + ni * 16 + (lane & 15);
          __hip_bfloat16 hv = __float2bfloat16(acc[mi][ni][q]);
          yrow[col] = *(unsigned short*)&hv;
        }
      }
    }
  }
}

// ---------------- combine: out[t] = sum_k g_k * (sum_z y2[z][s_k] + b2[e_k]) ----------------
__global__ __launch_bounds__(256) void combine_k(
    const unsigned short* __restrict__ y2, const float* __restrict__ b2,
    const int* __restrict__ t2i, const float* __restrict__ t2g,
    const int* __restrict__ slots, float* __restrict__ out, int T2) {
  const int t = blockIdx.x;
  const int c4 = threadIdx.x;   // 256 threads x float4 = 1024 cols
  const int s0 = slots[t * 2], s1 = slots[t * 2 + 1];
  const int e0 = t2i[t * 2], e1 = t2i[t * 2 + 1];
  const float g0 = t2g[t * 2], g1 = t2g[t * 2 + 1];
  const size_t sl = (size_t)T2 * D_DIM;
  float sum0[4] = {0.f,0.f,0.f,0.f}, sum1[4] = {0.f,0.f,0.f,0.f};
#pragma unroll
  for (int zz = 0; zz < 4; zz++) {
    ushort4 a = ((const ushort4*)(y2 + zz * sl + (size_t)s0 * D_DIM))[c4];
    ushort4 b = ((const ushort4*)(y2 + zz * sl + (size_t)s1 * D_DIM))[c4];
    sum0[0] += bf2f(a.x); sum0[1] += bf2f(a.y); sum0[2] += bf2f(a.z); sum0[3] += bf2f(a.w);
    sum1[0] += bf2f(b.x); sum1[1] += bf2f(b.y); sum1[2] += bf2f(b.z); sum1[3] += bf2f(b.w);
  }
  float4 bb0 = ((const float4*)(b2 + (size_t)e0 * D_DIM))[c4];
  float4 bb1 = ((const float4*)(b2 + (size_t)e1 * D_DIM))[c4];
  float4 o;
  o.x = g0 * (sum0[0] + bb0.x) + g1 * (sum1[0] + bb1.x);
  o.y = g0 * (sum0[1] + bb0.y) + g1 * (sum1[1] + bb1.y);
  o.z = g0 * (sum0[2] + bb0.z) + g1 * (sum1[2] + bb1.z);
  o.w = g0 * (sum0[3] + bb0.w) + g1 * (sum1[3] + bb1.w);
  ((float4*)(out + (size_t)t * D_DIM))[c4] = o;
}

extern "C" void kernel_launch(void* const* d_in, const int* in_sizes, int n_in,
                              void* d_out, int out_size, void* d_ws, size_t ws_size,
                              hipStream_t stream) {
  const float* x  = (const float*)d_in[0];
  const float* Wr = (const float*)d_in[1];
  const float* W1 = (const float*)d_in[2];
  const float* b1 = (const float*)d_in[3];
  const float* W2 = (const float*)d_in[4];
  const float* b2 = (const float*)d_in[5];
  float* out = (float*)d_out;

  const int T = in_sizes[0] / D_DIM;  // 4096
  const int T2 = T * 2;
  const int nblk = T / 4;

  char* ws = (char*)d_ws;
  size_t o = 0;
  unsigned short* xb  = (unsigned short*)(ws + o); o += (size_t)T * D_DIM * 2;
  unsigned short* W1b = (unsigned short*)(ws + o); o += (size_t)E_NUM * F_DIM * D_DIM * 2;
  unsigned short* W2b = (unsigned short*)(ws + o); o += (size_t)E_NUM * D_DIM * F_DIM * 2;
  unsigned short* hb  = (unsigned short*)(ws + o); o += (size_t)T2 * F_DIM * 2;
  int*   ctrl  = (int*)(ws + o);   o += 4096;
  int*   t2i   = (int*)(ws + o);   o += (size_t)T2 * 4;
  float* t2g   = (float*)(ws + o); o += (size_t)T2 * 4;
  int*   rmap  = (int*)(ws + o);   o += (size_t)T2 * 4;
  int*   slots = (int*)(ws + o);   o += (size_t)T2 * 4;
  float* usage_part = (float*)(ws + o); o += (size_t)nblk * E_NUM * 4;
  // y2 (4 x T2 x D bf16 = 67 MB) overlays W1b (67 MB) -- W1b is dead after gemm1.
  unsigned short* y2 = W1b;

  hipFuncSetAttribute((const void*)gemm1_k, hipFuncAttributeMaxDynamicSharedMemorySize, 49152);
  hipFuncSetAttribute((const void*)gemm2_k, hipFuncAttributeMaxDynamicSharedMemorySize, 49152);

  hipMemsetAsync(ctrl, 0, 4096, stream);

  cvt_k<<<1024, 256, 0, stream>>>(W1, W1b, E_NUM * F_DIM * D_DIM / 4);
  cvt_k<<<1024, 256, 0, stream>>>(W2, W2b, E_NUM * D_DIM * F_DIM / 4);

  router_k<<<nblk, 256, 0, stream>>>(x, Wr, t2i, t2g, usage_part, xb, T);
  reduce_k<<<1, 256, 0, stream>>>(usage_part, t2i, ctrl, out + (size_t)(out_size - 1), nblk, T2, T);
  scatter_k<<<(T + 255) / 256, 256, 0, stream>>>(t2i, ctrl, rmap, slots, T);

  gemm1_k<<<MAXT256 * 32, 512, 49152, stream>>>(xb, W1b, b1, hb, rmap, ctrl, T2);
  gemm2_k<<<MAXT256 * 32, 512, 49152, stream>>>(hb, W2b, y2, ctrl, T2);
  combine_k<<<T, 256, 0, stream>>>(y2, b2, t2i, t2g, slots, out, T2);
}